// Round 1
// baseline (870.630 us; speedup 1.0000x reference)
//
#include <hip/hip_runtime.h>
#include <math.h>

#define NEGV (-1e30f)

constexpr int B_ = 16;
constexpr int T_ = 512;
constexpr int E_ = 512;   // K of GEMM
constexpr int V_ = 5000;  // N of GEMM
constexpr int L_ = 64;
constexpr int S_ = 2 * L_ + 1;  // 129

// ---------- block reduction helper (256 threads = 4 waves of 64) ----------
__device__ __forceinline__ float blockReduceF(float v, bool is_max, volatile float* red) {
  int tid = threadIdx.x, lane = tid & 63, wid = tid >> 6;
#pragma unroll
  for (int off = 32; off > 0; off >>= 1) {
    float o = __shfl_down(v, off, 64);
    v = is_max ? fmaxf(v, o) : (v + o);
  }
  __syncthreads();  // protect red[] from any previous use
  if (lane == 0) red[wid] = v;
  __syncthreads();
  float r = red[0];
#pragma unroll
  for (int w = 1; w < 4; ++w) r = is_max ? fmaxf(r, (float)red[w]) : (r + (float)red[w]);
  return r;
}

// ---------- Kernel A: fp32 GEMM, C[mc x V] = A[mc x 512] * W[512 x V] + bias ----------
__global__ __launch_bounds__(256) void gemm64(const float* __restrict__ A,
                                              const float* __restrict__ W,
                                              const float* __restrict__ bias,
                                              float* __restrict__ C) {
  __shared__ float As[16][65];  // transposed A tile, +1 pad
  __shared__ float Bs[16][64];
  int tid = threadIdx.x;
  int bn = blockIdx.x * 64;
  int bm = blockIdx.y * 64;
  int tx = tid & 15, ty = tid >> 4;
  float acc[4][4] = {};
  int arow = tid >> 2, ac4 = (tid & 3) << 2;   // 64 rows x 4 loaders (float4 over K)
  int brow = tid >> 4, bc4 = (tid & 15) << 2;  // 16 k-rows x 16 loaders (float4 over N)
  for (int k0 = 0; k0 < E_; k0 += 16) {
    float4 av = *(const float4*)(A + (size_t)(bm + arow) * E_ + k0 + ac4);
    int n = bn + bc4;
    float4 bv = make_float4(0.f, 0.f, 0.f, 0.f);
    if (n + 3 < V_) bv = *(const float4*)(W + (size_t)(k0 + brow) * V_ + n);
    As[ac4 + 0][arow] = av.x;
    As[ac4 + 1][arow] = av.y;
    As[ac4 + 2][arow] = av.z;
    As[ac4 + 3][arow] = av.w;
    *(float4*)&Bs[brow][bc4] = bv;
    __syncthreads();
#pragma unroll
    for (int k = 0; k < 16; ++k) {
      float a[4], bb[4];
#pragma unroll
      for (int i = 0; i < 4; ++i) a[i] = As[k][ty * 4 + i];
#pragma unroll
      for (int j = 0; j < 4; ++j) bb[j] = Bs[k][tx * 4 + j];
#pragma unroll
      for (int i = 0; i < 4; ++i)
#pragma unroll
        for (int j = 0; j < 4; ++j) acc[i][j] += a[i] * bb[j];
    }
    __syncthreads();
  }
#pragma unroll
  for (int i = 0; i < 4; ++i) {
    int m = bm + ty * 4 + i;
#pragma unroll
    for (int j = 0; j < 4; ++j) {
      int n = bn + tx * 4 + j;
      if (n < V_) C[(size_t)m * V_ + n] = acc[i][j] + bias[n];
    }
  }
}

// ---------- Kernel B: per-row log-softmax stats + KD term + CTC emission gather ----------
__global__ __launch_bounds__(256) void row_fused(const float* __restrict__ Cc,
                                                 const float* __restrict__ soft,
                                                 const int* __restrict__ hlens,
                                                 const int* __restrict__ targets,
                                                 float* __restrict__ cxe,
                                                 float* __restrict__ emit, int r0) {
  int r = blockIdx.x;
  int row = r0 + r;
  int bidx = row >> 9;  // / T_
  int t = row & (T_ - 1);
  const float4* lrow = (const float4*)(Cc + (size_t)r * V_);
  const float4* srow = (const float4*)(soft + (size_t)row * V_);
  __shared__ __align__(16) float Ls[V_];
  __shared__ __align__(16) float Ss[V_];
  __shared__ float red[4];
  int tid = threadIdx.x;
  float maxl = -INFINITY, maxs = -INFINITY;
  for (int i = tid; i < V_ / 4; i += 256) {
    float4 lv = lrow[i], sv = srow[i];
    *(float4*)&Ls[i * 4] = lv;
    *(float4*)&Ss[i * 4] = sv;
    maxl = fmaxf(fmaxf(fmaxf(maxl, lv.x), fmaxf(lv.y, lv.z)), lv.w);
    maxs = fmaxf(fmaxf(fmaxf(maxs, sv.x), fmaxf(sv.y, sv.z)), sv.w);
  }
  maxl = blockReduceF(maxl, true, red);
  maxs = blockReduceF(maxs, true, red);
  float suml = 0.f, sums = 0.f, dot = 0.f;
  for (int i = tid; i < V_; i += 256) {
    float l = Ls[i], s = Ss[i];
    suml += expf(l - maxl);
    float e = expf(s - maxs);
    sums += e;
    dot += e * l;
  }
  suml = blockReduceF(suml, false, red);
  sums = blockReduceF(sums, false, red);
  dot = blockReduceF(dot, false, red);
  float lse = maxl + logf(suml);
  if (tid == 0) {
    // cxe = -(sum_v p_v * (l_v - lse)) = lse - dot/sums, masked by t < hlen
    cxe[row] = (t < hlens[bidx]) ? (lse - dot / sums) : 0.0f;
  }
  if (tid < S_) {
    int idx = (tid & 1) ? targets[bidx * L_ + (tid >> 1)] : 0;  // blank = 0
    emit[((size_t)bidx * T_ + t) * S_ + tid] = Ls[idx] - lse;
  }
}

// ---------- Kernel C: CTC forward recursion per batch element ----------
__global__ __launch_bounds__(256) void ctc_fwd(const float* __restrict__ emit,
                                               const int* __restrict__ hlens,
                                               const int* __restrict__ targets,
                                               const int* __restrict__ olens,
                                               float* __restrict__ ctc_out) {
  int b = blockIdx.x;
  int s = threadIdx.x;
  __shared__ float alpha[2][S_];
  const float* Eb = emit + (size_t)b * T_ * S_;
  bool active = s < S_;
  bool allow2 = false;
  if (active && (s & 1) && s >= 3) {  // odd labels with s>=2
    int i = s >> 1;
    allow2 = (targets[b * L_ + i] != targets[b * L_ + i - 1]);
  }
  if (active) alpha[0][s] = (s == 0) ? Eb[0] : (s == 1 ? Eb[1] : NEGV);
  __syncthreads();
  int ilen = hlens[b];
  int cur = 0;
  for (int t = 1; t < T_; ++t) {
    if (t >= ilen) break;  // alpha frozen past ilen-1 (uniform branch per block)
    float nv = 0.f;
    if (active) {
      float a0 = alpha[cur][s];
      float s1 = (s >= 1) ? alpha[cur][s - 1] : NEGV;
      float s2 = allow2 ? alpha[cur][s - 2] : NEGV;
      float m = fmaxf(a0, fmaxf(s1, s2));
      nv = m + logf(expf(a0 - m) + expf(s1 - m) + expf(s2 - m)) + Eb[(size_t)t * S_ + s];
    }
    if (active) alpha[cur ^ 1][s] = nv;
    cur ^= 1;
    __syncthreads();
  }
  if (s == 0) {
    int end = 2 * olens[b];
    float a = alpha[cur][end], a1 = alpha[cur][end - 1];
    float m = fmaxf(a, a1);
    float ll = m + logf(expf(a - m) + expf(a1 - m));
    float loss = -ll;
    if (loss > 1e20f) loss = 0.0f;  // zero_infinity
    ctc_out[b] = loss;
  }
}

// ---------- Kernel D: final combine ----------
__global__ __launch_bounds__(256) void final_reduce(const float* __restrict__ cxe,
                                                    const float* __restrict__ ctco,
                                                    float* __restrict__ out) {
  __shared__ float red[4];
  float s = 0.f;
  for (int i = threadIdx.x; i < B_ * T_; i += 256) s += cxe[i];
  s = blockReduceF(s, false, red);
  if (threadIdx.x == 0) {
    float c = 0.f;
    for (int b = 0; b < B_; ++b) c += ctco[b];
    // KD_FACTOR = 0.5
    out[0] = 0.5f * (s / (float)B_) + 0.5f * (c / (float)B_);
  }
}

extern "C" void kernel_launch(void* const* d_in, const int* in_sizes, int n_in,
                              void* d_out, int out_size, void* d_ws, size_t ws_size,
                              hipStream_t stream) {
  const float* hs = (const float*)d_in[0];       // [16,512,512]
  const float* soft = (const float*)d_in[1];     // [16,512,5000]
  const float* W = (const float*)d_in[2];        // [512,5000]
  const float* bias = (const float*)d_in[3];     // [5000]
  const int* hlens = (const int*)d_in[4];        // [16]
  const int* targets = (const int*)d_in[5];      // [16,64]
  const int* olens = (const int*)d_in[6];        // [16]
  float* out = (float*)d_out;

  // workspace layout
  float* emit = (float*)d_ws;                         // B*T*S floats (~4.2 MB)
  size_t emit_n = (size_t)B_ * T_ * S_;
  float* cxe = emit + emit_n;                         // B*T floats
  float* ctco = cxe + (size_t)B_ * T_;                // B floats
  float* logits = ctco + 16;                          // chunk buffer
  size_t used = (size_t)((char*)logits - (char*)d_ws);
  size_t avail = (ws_size > used) ? (ws_size - used) : 0;
  int max_rows = (int)(avail / ((size_t)V_ * sizeof(float)));
  int chunk = max_rows & ~63;  // multiple of 64
  int total = B_ * T_;
  if (chunk > total) chunk = total;
  if (chunk < 64) chunk = 64;  // require modest workspace

  dim3 blk(256);
  for (int r0 = 0; r0 < total; r0 += chunk) {
    int mc = total - r0;
    if (mc > chunk) mc = chunk;
    dim3 g1((V_ + 63) / 64, mc / 64);
    hipLaunchKernelGGL(gemm64, g1, blk, 0, stream, hs + (size_t)r0 * E_, W, bias, logits);
    hipLaunchKernelGGL(row_fused, dim3(mc), blk, 0, stream, logits, soft, hlens, targets,
                       cxe, emit, r0);
  }
  hipLaunchKernelGGL(ctc_fwd, dim3(B_), blk, 0, stream, emit, hlens, targets, olens, ctco);
  hipLaunchKernelGGL(final_reduce, dim3(1), blk, 0, stream, cxe, ctco, out);
}

// Round 2
// 347.136 us; speedup vs baseline: 2.5080x; 2.5080x over previous
//
#include <hip/hip_runtime.h>
#include <math.h>

#define NEGV (-1e30f)

constexpr int B_ = 16;
constexpr int T_ = 512;
constexpr int E_ = 512;    // K of GEMM
constexpr int V_ = 5000;   // true N
constexpr int VP_ = 5120;  // padded N (multiple of 128)
constexpr int L_ = 64;
constexpr int S_ = 2 * L_ + 1;  // 129

typedef __attribute__((ext_vector_type(8))) short bf16x8;
typedef __attribute__((ext_vector_type(4))) float f32x4;

#define GLOAD_LDS16(g, l)                                                              \
  __builtin_amdgcn_global_load_lds((const __attribute__((address_space(1))) void*)(g), \
                                   (__attribute__((address_space(3))) void*)(l), 16, 0, 0)

__device__ __forceinline__ unsigned short f2bf(float x) {
  unsigned int u = __float_as_uint(x);
  unsigned int r = (u + 0x7fffu + ((u >> 16) & 1u)) >> 16;  // round-to-nearest-even
  return (unsigned short)r;
}

// ---------- block reduction helper (256 threads = 4 waves of 64) ----------
__device__ __forceinline__ float blockReduceF(float v, bool is_max, volatile float* red) {
  int tid = threadIdx.x, lane = tid & 63, wid = tid >> 6;
#pragma unroll
  for (int off = 32; off > 0; off >>= 1) {
    float o = __shfl_down(v, off, 64);
    v = is_max ? fmaxf(v, o) : (v + o);
  }
  __syncthreads();
  if (lane == 0) red[wid] = v;
  __syncthreads();
  float r = red[0];
#pragma unroll
  for (int w = 1; w < 4; ++w) r = is_max ? fmaxf(r, (float)red[w]) : (r + (float)red[w]);
  return r;
}

// ---------- conversion: hs_pad f32 -> bf16 (row-major [M][512]) ----------
__global__ __launch_bounds__(256) void convA(const float* __restrict__ X,
                                             unsigned short* __restrict__ Y, int n4) {
  int i = blockIdx.x * 256 + threadIdx.x;
  if (i >= n4) return;
  float4 v = ((const float4*)X)[i];
  ushort4 o;
  o.x = f2bf(v.x); o.y = f2bf(v.y); o.z = f2bf(v.z); o.w = f2bf(v.w);
  ((ushort4*)Y)[i] = o;
}

// ---------- conversion: W [512][5000] f32 -> W_T [5120][512] bf16 ----------
__global__ __launch_bounds__(256) void convW(const float* __restrict__ W,
                                             unsigned short* __restrict__ Wt) {
  __shared__ float tile[32][33];
  int n0 = blockIdx.x * 32, k0 = blockIdx.y * 32;
  int tid = threadIdx.x;
  int tx = tid & 31, ty = tid >> 5;  // 8 rows per pass
#pragma unroll
  for (int p = 0; p < 4; ++p) {
    int k = k0 + ty + p * 8, n = n0 + tx;
    tile[ty + p * 8][tx] = (n < V_) ? W[(size_t)k * V_ + n] : 0.0f;
  }
  __syncthreads();
#pragma unroll
  for (int p = 0; p < 4; ++p) {
    int n = n0 + ty + p * 8, k = k0 + tx;
    Wt[(size_t)n * E_ + k] = f2bf(tile[tx][ty + p * 8]);
  }
}

// ---------- Kernel A: bf16 MFMA GEMM, C[mc x VP] = A[mc x 512] * Wt^T + bias ----------
// A: [mc][512] bf16 row-major; Wt: [5120][512] bf16 (N-major); C f32 [mc][5120]
__global__ __launch_bounds__(256) void gemm_mfma(const unsigned short* __restrict__ A,
                                                 const unsigned short* __restrict__ Wt,
                                                 const float* __restrict__ bias,
                                                 float* __restrict__ C) {
  __shared__ unsigned short As[128 * 32];  // [row][k] rows of 32 bf16 (64B)
  __shared__ unsigned short Bs[128 * 32];  // [n][k]
  int tid = threadIdx.x;
  int l = tid & 63, wid = tid >> 6;
  int lane15 = l & 15, lhalf = l >> 4;  // 0..3
  int wr = wid >> 1, wc = wid & 1;      // wave grid 2x2, each 64x64
  int bm = blockIdx.y * 128;
  int bn = blockIdx.x * 128;

  f32x4 acc[4][4] = {};

  // staging addresses: each wave stages 32 rows of A and 32 rows of B per K-step
  int srow = l >> 2;          // 0..15 within 16-row group
  int scol = (l & 3) * 8;     // element offset within 32-elem row
  for (int k0 = 0; k0 < E_; k0 += 32) {
#pragma unroll
    for (int i = 0; i < 2; ++i) {
      int rb = wid * 32 + i * 16;
      GLOAD_LDS16(A + (size_t)(bm + rb + srow) * E_ + k0 + scol, &As[rb * 32]);
      GLOAD_LDS16(Wt + (size_t)(bn + rb + srow) * E_ + k0 + scol, &Bs[rb * 32]);
    }
    __syncthreads();
    bf16x8 af[4], bf[4];
#pragma unroll
    for (int m = 0; m < 4; ++m)
      af[m] = *(const bf16x8*)&As[(wr * 64 + m * 16 + lane15) * 32 + lhalf * 8];
#pragma unroll
    for (int n = 0; n < 4; ++n)
      bf[n] = *(const bf16x8*)&Bs[(wc * 64 + n * 16 + lane15) * 32 + lhalf * 8];
#pragma unroll
    for (int m = 0; m < 4; ++m)
#pragma unroll
      for (int n = 0; n < 4; ++n)
        acc[m][n] = __builtin_amdgcn_mfma_f32_16x16x32_bf16(af[m], bf[n], acc[m][n], 0, 0, 0);
    __syncthreads();
  }

  // epilogue: C/D layout col=lane&15, row=(lane>>4)*4+j
#pragma unroll
  for (int n = 0; n < 4; ++n) {
    int col = bn + wc * 64 + n * 16 + lane15;
    float bv = (col < V_) ? bias[col] : 0.0f;
#pragma unroll
    for (int m = 0; m < 4; ++m) {
      int row0 = bm + wr * 64 + m * 16 + lhalf * 4;
#pragma unroll
      for (int j = 0; j < 4; ++j) {
        C[(size_t)(row0 + j) * VP_ + col] = acc[m][n][j] + bv;
      }
    }
  }
}

// ---------- Kernel B: per-row log-softmax stats + KD term + CTC emission gather ----------
__global__ __launch_bounds__(256) void row_fused(const float* __restrict__ Cc,
                                                 const float* __restrict__ soft,
                                                 const int* __restrict__ hlens,
                                                 const int* __restrict__ targets,
                                                 float* __restrict__ cxe,
                                                 float* __restrict__ emit, int r0) {
  int r = blockIdx.x;
  int row = r0 + r;
  int bidx = row >> 9;  // / T_
  int t = row & (T_ - 1);
  const float4* lrow = (const float4*)(Cc + (size_t)r * VP_);
  const float4* srow = (const float4*)(soft + (size_t)row * V_);
  __shared__ __align__(16) float Ls[V_];
  __shared__ __align__(16) float Ss[V_];
  __shared__ float red[4];
  int tid = threadIdx.x;
  float maxl = -INFINITY, maxs = -INFINITY;
  for (int i = tid; i < V_ / 4; i += 256) {
    float4 lv = lrow[i], sv = srow[i];
    *(float4*)&Ls[i * 4] = lv;
    *(float4*)&Ss[i * 4] = sv;
    maxl = fmaxf(fmaxf(fmaxf(maxl, lv.x), fmaxf(lv.y, lv.z)), lv.w);
    maxs = fmaxf(fmaxf(fmaxf(maxs, sv.x), fmaxf(sv.y, sv.z)), sv.w);
  }
  maxl = blockReduceF(maxl, true, red);
  maxs = blockReduceF(maxs, true, red);
  float suml = 0.f, sums = 0.f, dot = 0.f;
  for (int i = tid; i < V_; i += 256) {
    float l = Ls[i], s = Ss[i];
    suml += expf(l - maxl);
    float e = expf(s - maxs);
    sums += e;
    dot += e * l;
  }
  suml = blockReduceF(suml, false, red);
  sums = blockReduceF(sums, false, red);
  dot = blockReduceF(dot, false, red);
  float lse = maxl + logf(suml);
  if (tid == 0) {
    cxe[row] = (t < hlens[bidx]) ? (lse - dot / sums) : 0.0f;
  }
  if (tid < S_) {
    int idx = (tid & 1) ? targets[bidx * L_ + (tid >> 1)] : 0;  // blank = 0
    emit[((size_t)bidx * T_ + t) * S_ + tid] = Ls[idx] - lse;
  }
}

// ---------- Kernel C: CTC forward recursion per batch element ----------
__global__ __launch_bounds__(256) void ctc_fwd(const float* __restrict__ emit,
                                               const int* __restrict__ hlens,
                                               const int* __restrict__ targets,
                                               const int* __restrict__ olens,
                                               float* __restrict__ ctc_out) {
  int b = blockIdx.x;
  int s = threadIdx.x;
  __shared__ float alpha[2][S_];
  const float* Eb = emit + (size_t)b * T_ * S_;
  bool active = s < S_;
  bool allow2 = false;
  if (active && (s & 1) && s >= 3) {
    int i = s >> 1;
    allow2 = (targets[b * L_ + i] != targets[b * L_ + i - 1]);
  }
  if (active) alpha[0][s] = (s == 0) ? Eb[0] : (s == 1 ? Eb[1] : NEGV);
  __syncthreads();
  int ilen = hlens[b];
  int cur = 0;
  for (int t = 1; t < T_; ++t) {
    if (t >= ilen) break;
    float nv = 0.f;
    if (active) {
      float a0 = alpha[cur][s];
      float s1 = (s >= 1) ? alpha[cur][s - 1] : NEGV;
      float s2 = allow2 ? alpha[cur][s - 2] : NEGV;
      float m = fmaxf(a0, fmaxf(s1, s2));
      nv = m + logf(expf(a0 - m) + expf(s1 - m) + expf(s2 - m)) + Eb[(size_t)t * S_ + s];
    }
    if (active) alpha[cur ^ 1][s] = nv;
    cur ^= 1;
    __syncthreads();
  }
  if (s == 0) {
    int end = 2 * olens[b];
    float a = alpha[cur][end], a1 = alpha[cur][end - 1];
    float m = fmaxf(a, a1);
    float ll = m + logf(expf(a - m) + expf(a1 - m));
    float loss = -ll;
    if (loss > 1e20f) loss = 0.0f;
    ctc_out[b] = loss;
  }
}

// ---------- Kernel D: final combine ----------
__global__ __launch_bounds__(256) void final_reduce(const float* __restrict__ cxe,
                                                    const float* __restrict__ ctco,
                                                    float* __restrict__ out) {
  __shared__ float red[4];
  float s = 0.f;
  for (int i = threadIdx.x; i < B_ * T_; i += 256) s += cxe[i];
  s = blockReduceF(s, false, red);
  if (threadIdx.x == 0) {
    float c = 0.f;
    for (int b = 0; b < B_; ++b) c += ctco[b];
    out[0] = 0.5f * (s / (float)B_) + 0.5f * (c / (float)B_);
  }
}

extern "C" void kernel_launch(void* const* d_in, const int* in_sizes, int n_in,
                              void* d_out, int out_size, void* d_ws, size_t ws_size,
                              hipStream_t stream) {
  const float* hs = (const float*)d_in[0];     // [16,512,512]
  const float* soft = (const float*)d_in[1];   // [16,512,5000]
  const float* W = (const float*)d_in[2];      // [512,5000]
  const float* bias = (const float*)d_in[3];   // [5000]
  const int* hlens = (const int*)d_in[4];      // [16]
  const int* targets = (const int*)d_in[5];    // [16,64]
  const int* olens = (const int*)d_in[6];      // [16]
  float* out = (float*)d_out;

  // workspace layout (all segments 16B-aligned)
  size_t emit_n = (size_t)B_ * T_ * S_;  // 1,056,768
  float* emit = (float*)d_ws;
  float* cxe = emit + emit_n;              // 8192
  float* ctco = cxe + (size_t)B_ * T_;     // 16
  unsigned short* Abf = (unsigned short*)(ctco + 16);   // 8192*512 bf16
  unsigned short* Wt = Abf + (size_t)B_ * T_ * E_;      // 5120*512 bf16
  float* logits = (float*)(Wt + (size_t)VP_ * E_);      // chunk buffer [rows][5120]
  size_t used = (size_t)((char*)logits - (char*)d_ws);
  size_t avail = (ws_size > used) ? (ws_size - used) : 0;
  int max_rows = (int)(avail / ((size_t)VP_ * sizeof(float)));
  int chunk = max_rows & ~127;  // multiple of 128
  int total = B_ * T_;          // 8192
  if (chunk > total) chunk = total;
  if (chunk < 128) chunk = 128;

  dim3 blk(256);
  // one-time conversions
  {
    int n4 = total * E_ / 4;  // 1,048,576 float4 groups
    hipLaunchKernelGGL(convA, dim3((n4 + 255) / 256), blk, 0, stream, hs, Abf, n4);
    hipLaunchKernelGGL(convW, dim3(VP_ / 32, E_ / 32), blk, 0, stream, W, Wt);
  }

  for (int r0 = 0; r0 < total; r0 += chunk) {
    int mc = total - r0;
    if (mc > chunk) mc = chunk;
    dim3 g1(VP_ / 128, mc / 128);
    hipLaunchKernelGGL(gemm_mfma, g1, blk, 0, stream, Abf + (size_t)r0 * E_, Wt, bias, logits);
    hipLaunchKernelGGL(row_fused, dim3(mc), blk, 0, stream, logits, soft, hlens, targets,
                       cxe, emit, r0);
  }
  hipLaunchKernelGGL(ctc_fwd, dim3(B_), blk, 0, stream, emit, hlens, targets, olens, ctco);
  hipLaunchKernelGGL(final_reduce, dim3(1), blk, 0, stream, cxe, ctco, out);
}

// Round 3
// 269.148 us; speedup vs baseline: 3.2348x; 1.2898x over previous
//
#include <hip/hip_runtime.h>
#include <math.h>

#define NEGV (-1e30f)
#define LOG2E 1.4426950408889634f
#define LN2 0.6931471805599453f
#define NEGL (-1.4426950e30f)  // NEGV * LOG2E

constexpr int B_ = 16;
constexpr int T_ = 512;
constexpr int E_ = 512;    // K of GEMM
constexpr int V_ = 5000;   // true N
constexpr int VP_ = 5120;  // padded N (multiple of 128)
constexpr int L_ = 64;
constexpr int S_ = 2 * L_ + 1;  // 129
constexpr int SP_ = 132;        // padded emit stride (floats, 8B-aligned pairs)

typedef __attribute__((ext_vector_type(8))) short bf16x8;
typedef __attribute__((ext_vector_type(4))) float f32x4;

#define GLOAD_LDS16(g, l)                                                              \
  __builtin_amdgcn_global_load_lds((const __attribute__((address_space(1))) void*)(g), \
                                   (__attribute__((address_space(3))) void*)(l), 16, 0, 0)

__device__ __forceinline__ unsigned short f2bf(float x) {
  unsigned int u = __float_as_uint(x);
  unsigned int r = (u + 0x7fffu + ((u >> 16) & 1u)) >> 16;  // round-to-nearest-even
  return (unsigned short)r;
}

__device__ __forceinline__ float hexp2(float x) { return __builtin_amdgcn_exp2f(x); }
__device__ __forceinline__ float hlog2(float x) { return __builtin_amdgcn_logf(x); }

// ---------- block reduction helper (256 threads = 4 waves of 64) ----------
__device__ __forceinline__ float blockReduceF(float v, bool is_max, volatile float* red) {
  int tid = threadIdx.x, lane = tid & 63, wid = tid >> 6;
#pragma unroll
  for (int off = 32; off > 0; off >>= 1) {
    float o = __shfl_down(v, off, 64);
    v = is_max ? fmaxf(v, o) : (v + o);
  }
  __syncthreads();
  if (lane == 0) red[wid] = v;
  __syncthreads();
  float r = red[0];
#pragma unroll
  for (int w = 1; w < 4; ++w) r = is_max ? fmaxf(r, (float)red[w]) : (r + (float)red[w]);
  return r;
}

// ---------- conversion: hs_pad f32 -> bf16 (row-major [M][512]) ----------
__global__ __launch_bounds__(256) void convA(const float* __restrict__ X,
                                             unsigned short* __restrict__ Y, int n4) {
  int i = blockIdx.x * 256 + threadIdx.x;
  if (i >= n4) return;
  float4 v = ((const float4*)X)[i];
  ushort4 o;
  o.x = f2bf(v.x); o.y = f2bf(v.y); o.z = f2bf(v.z); o.w = f2bf(v.w);
  ((ushort4*)Y)[i] = o;
}

// ---------- conversion: W [512][5000] f32 -> W_T [5120][512] bf16 ----------
__global__ __launch_bounds__(256) void convW(const float* __restrict__ W,
                                             unsigned short* __restrict__ Wt) {
  __shared__ float tile[32][33];
  int n0 = blockIdx.x * 32, k0 = blockIdx.y * 32;
  int tid = threadIdx.x;
  int tx = tid & 31, ty = tid >> 5;  // 8 rows per pass
#pragma unroll
  for (int p = 0; p < 4; ++p) {
    int k = k0 + ty + p * 8, n = n0 + tx;
    tile[ty + p * 8][tx] = (n < V_) ? W[(size_t)k * V_ + n] : 0.0f;
  }
  __syncthreads();
#pragma unroll
  for (int p = 0; p < 4; ++p) {
    int n = n0 + ty + p * 8, k = k0 + tx;
    Wt[(size_t)n * E_ + k] = f2bf(tile[tx][ty + p * 8]);
  }
}

// ---------- Kernel A: bf16 MFMA GEMM ----------
__global__ __launch_bounds__(256) void gemm_mfma(const unsigned short* __restrict__ A,
                                                 const unsigned short* __restrict__ Wt,
                                                 const float* __restrict__ bias,
                                                 float* __restrict__ C) {
  __shared__ unsigned short As[128 * 32];
  __shared__ unsigned short Bs[128 * 32];
  int tid = threadIdx.x;
  int l = tid & 63, wid = tid >> 6;
  int lane15 = l & 15, lhalf = l >> 4;
  int wr = wid >> 1, wc = wid & 1;
  int bm = blockIdx.y * 128;
  int bn = blockIdx.x * 128;

  f32x4 acc[4][4] = {};

  int srow = l >> 2;
  int scol = (l & 3) * 8;
  for (int k0 = 0; k0 < E_; k0 += 32) {
#pragma unroll
    for (int i = 0; i < 2; ++i) {
      int rb = wid * 32 + i * 16;
      GLOAD_LDS16(A + (size_t)(bm + rb + srow) * E_ + k0 + scol, &As[rb * 32]);
      GLOAD_LDS16(Wt + (size_t)(bn + rb + srow) * E_ + k0 + scol, &Bs[rb * 32]);
    }
    __syncthreads();
    bf16x8 af[4], bf[4];
#pragma unroll
    for (int m = 0; m < 4; ++m)
      af[m] = *(const bf16x8*)&As[(wr * 64 + m * 16 + lane15) * 32 + lhalf * 8];
#pragma unroll
    for (int n = 0; n < 4; ++n)
      bf[n] = *(const bf16x8*)&Bs[(wc * 64 + n * 16 + lane15) * 32 + lhalf * 8];
#pragma unroll
    for (int m = 0; m < 4; ++m)
#pragma unroll
      for (int n = 0; n < 4; ++n)
        acc[m][n] = __builtin_amdgcn_mfma_f32_16x16x32_bf16(af[m], bf[n], acc[m][n], 0, 0, 0);
    __syncthreads();
  }

#pragma unroll
  for (int n = 0; n < 4; ++n) {
    int col = bn + wc * 64 + n * 16 + lane15;
    float bv = (col < V_) ? bias[col] : 0.0f;
#pragma unroll
    for (int m = 0; m < 4; ++m) {
      int row0 = bm + wr * 64 + m * 16 + lhalf * 4;
#pragma unroll
      for (int j = 0; j < 4; ++j) {
        C[(size_t)(row0 + j) * VP_ + col] = acc[m][n][j] + bv;
      }
    }
  }
}

// ---------- Kernel B: per-row log-softmax stats + KD term + CTC emission gather ----------
__global__ __launch_bounds__(256) void row_fused(const float* __restrict__ Cc,
                                                 const float* __restrict__ soft,
                                                 const int* __restrict__ hlens,
                                                 const int* __restrict__ targets,
                                                 float* __restrict__ cxe,
                                                 float* __restrict__ emit, int r0) {
  int r = blockIdx.x;
  int row = r0 + r;
  int bidx = row >> 9;
  int t = row & (T_ - 1);
  const float4* lrow = (const float4*)(Cc + (size_t)r * VP_);
  const float4* srow = (const float4*)(soft + (size_t)row * V_);
  __shared__ __align__(16) float Ls[V_];
  __shared__ __align__(16) float Ss[V_];
  __shared__ float red[4];
  int tid = threadIdx.x;
  float maxl = -INFINITY, maxs = -INFINITY;
  for (int i = tid; i < V_ / 4; i += 256) {
    float4 lv = lrow[i], sv = srow[i];
    *(float4*)&Ls[i * 4] = lv;
    *(float4*)&Ss[i * 4] = sv;
    maxl = fmaxf(fmaxf(fmaxf(maxl, lv.x), fmaxf(lv.y, lv.z)), lv.w);
    maxs = fmaxf(fmaxf(fmaxf(maxs, sv.x), fmaxf(sv.y, sv.z)), sv.w);
  }
  maxl = blockReduceF(maxl, true, red);
  maxs = blockReduceF(maxs, true, red);
  float suml = 0.f, sums = 0.f, dot = 0.f;
  for (int i = tid; i < V_; i += 256) {
    float l = Ls[i], s = Ss[i];
    suml += hexp2((l - maxl) * LOG2E);
    float e = hexp2((s - maxs) * LOG2E);
    sums += e;
    dot += e * l;
  }
  suml = blockReduceF(suml, false, red);
  sums = blockReduceF(sums, false, red);
  dot = blockReduceF(dot, false, red);
  float lse = maxl + hlog2(suml) * LN2;
  if (tid == 0) {
    cxe[row] = (t < hlens[bidx]) ? (lse - dot / sums) : 0.0f;
  }
  if (tid < S_) {
    int idx = (tid & 1) ? targets[bidx * L_ + (tid >> 1)] : 0;  // blank = 0
    // store emission log-prob pre-scaled to log2 domain for the CTC kernel
    emit[((size_t)bidx * T_ + t) * SP_ + tid] = (Ls[idx] - lse) * LOG2E;
  }
}

// ---------- Kernel C: CTC forward, one wave per batch, register alpha ----------
// lane l holds states s=2l, 2l+1; lane 63 additionally s=128. log2 domain.
struct CtcState {
  float a0, a1, a2;
  bool allow2;
  int lane;
};

__device__ __forceinline__ void ctc_step(CtcState& st, float e0, float e1, float e2) {
  float ua1 = __shfl_up(st.a1, 1, 64);  // old alpha[2l-1]
  if (st.lane == 0) ua1 = NEGL;
  // s=2l (blank): LSE2(a0, ua1)
  float m0 = fmaxf(st.a0, ua1);
  float n0 = m0 + hlog2(hexp2(st.a0 - m0) + hexp2(ua1 - m0)) + e0;
  // s=2l+1 (label): LSE3(a1, a0, allow2?ua1)
  float s2 = st.allow2 ? ua1 : NEGL;
  float m1 = fmaxf(fmaxf(st.a1, st.a0), s2);
  float n1 = m1 + hlog2(hexp2(st.a1 - m1) + hexp2(st.a0 - m1) + hexp2(s2 - m1)) + e1;
  // s=128 (blank, lane 63 only; uses lane-local old a1): LSE2(a2, a1)
  float m2 = fmaxf(st.a2, st.a1);
  float n2 = m2 + hlog2(hexp2(st.a2 - m2) + hexp2(st.a1 - m2)) + e2;
  st.a0 = n0; st.a1 = n1; st.a2 = n2;
}

__global__ __launch_bounds__(64) void ctc_fwd(const float* __restrict__ emit,
                                              const int* __restrict__ hlens,
                                              const int* __restrict__ targets,
                                              const int* __restrict__ olens,
                                              float* __restrict__ ctc_out) {
  int b = blockIdx.x;
  int l = threadIdx.x;  // 0..63
  const float* Eb = emit + (size_t)b * T_ * SP_;
  CtcState st;
  st.lane = l;
  st.allow2 = false;
  if (l >= 1) st.allow2 = (targets[b * L_ + l] != targets[b * L_ + l - 1]);
  // init from t=0
  {
    float2 e01 = *(const float2*)(Eb + 2 * l);
    st.a0 = (l == 0) ? e01.x : NEGL;
    st.a1 = (l == 0) ? e01.y : NEGL;
    st.a2 = NEGL;
  }
  int ilen = hlens[b];

#define LDE(tt) (*(const float2*)(Eb + (size_t)(tt) * SP_ + 2 * l))
#define LDX(tt) (*(const float2*)(Eb + (size_t)(tt) * SP_ + 128))

  float2 c0 = LDE(1), x0 = LDX(1);
  float2 c1 = LDE(2), x1 = LDX(2);
  float2 c2 = LDE(3), x2 = LDX(3);
  float2 c3 = LDE(4), x3 = LDX(4);
  int t = 1;
  for (; t + 3 <= ilen - 1; t += 4) {
    float2 p0 = LDE(t + 4), q0 = LDX(t + 4);
    float2 p1 = LDE(t + 5), q1 = LDX(t + 5);
    float2 p2 = LDE(t + 6), q2 = LDX(t + 6);
    float2 p3 = LDE(t + 7), q3 = LDX(t + 7);
    ctc_step(st, c0.x, c0.y, x0.x);
    ctc_step(st, c1.x, c1.y, x1.x);
    ctc_step(st, c2.x, c2.y, x2.x);
    ctc_step(st, c3.x, c3.y, x3.x);
    c0 = p0; x0 = q0; c1 = p1; x1 = q1; c2 = p2; x2 = q2; c3 = p3; x3 = q3;
  }
  for (; t <= ilen - 1; ++t) {
    ctc_step(st, c0.x, c0.y, x0.x);
    c0 = c1; x0 = x1; c1 = c2; x1 = x2; c2 = c3; x2 = x3;
  }
#undef LDE
#undef LDX

  int end = 2 * olens[b];  // 64..128, even
  float aE = (end == 128) ? __shfl(st.a2, 63, 64) : __shfl(st.a0, end >> 1, 64);
  float aE1 = __shfl(st.a1, (end >> 1) - 1, 64);
  if (l == 0) {
    float m = fmaxf(aE, aE1);
    float ll2 = m + hlog2(hexp2(aE - m) + hexp2(aE1 - m));
    float loss = -(ll2 * LN2);
    if (loss > 1e20f) loss = 0.0f;  // zero_infinity
    ctc_out[b] = loss;
  }
}

// ---------- Kernel D: final combine ----------
__global__ __launch_bounds__(256) void final_reduce(const float* __restrict__ cxe,
                                                    const float* __restrict__ ctco,
                                                    float* __restrict__ out) {
  __shared__ float red[4];
  float s = 0.f;
  for (int i = threadIdx.x; i < B_ * T_; i += 256) s += cxe[i];
  s = blockReduceF(s, false, red);
  if (threadIdx.x == 0) {
    float c = 0.f;
    for (int b = 0; b < B_; ++b) c += ctco[b];
    out[0] = 0.5f * (s / (float)B_) + 0.5f * (c / (float)B_);
  }
}

extern "C" void kernel_launch(void* const* d_in, const int* in_sizes, int n_in,
                              void* d_out, int out_size, void* d_ws, size_t ws_size,
                              hipStream_t stream) {
  const float* hs = (const float*)d_in[0];
  const float* soft = (const float*)d_in[1];
  const float* W = (const float*)d_in[2];
  const float* bias = (const float*)d_in[3];
  const int* hlens = (const int*)d_in[4];
  const int* targets = (const int*)d_in[5];
  const int* olens = (const int*)d_in[6];
  float* out = (float*)d_out;

  // workspace layout (emit padded: +16 rows of slack for prefetch overruns)
  size_t emit_n = (size_t)(B_ * T_ + 16) * SP_;
  float* emit = (float*)d_ws;
  float* cxe = emit + emit_n;
  float* ctco = cxe + (size_t)B_ * T_;
  unsigned short* Abf = (unsigned short*)(ctco + 16);
  unsigned short* Wt = Abf + (size_t)B_ * T_ * E_;
  float* logits = (float*)(Wt + (size_t)VP_ * E_);
  size_t used = (size_t)((char*)logits - (char*)d_ws);
  size_t avail = (ws_size > used) ? (ws_size - used) : 0;
  int max_rows = (int)(avail / ((size_t)VP_ * sizeof(float)));
  int chunk = max_rows & ~127;
  int total = B_ * T_;
  if (chunk > total) chunk = total;
  if (chunk < 128) chunk = 128;

  dim3 blk(256);
  {
    int n4 = total * E_ / 4;
    hipLaunchKernelGGL(convA, dim3((n4 + 255) / 256), blk, 0, stream, hs, Abf, n4);
    hipLaunchKernelGGL(convW, dim3(VP_ / 32, E_ / 32), blk, 0, stream, W, Wt);
  }

  for (int r0 = 0; r0 < total; r0 += chunk) {
    int mc = total - r0;
    if (mc > chunk) mc = chunk;
    dim3 g1(VP_ / 128, mc / 128);
    hipLaunchKernelGGL(gemm_mfma, g1, blk, 0, stream, Abf + (size_t)r0 * E_, Wt, bias, logits);
    hipLaunchKernelGGL(row_fused, dim3(mc), blk, 0, stream, logits, soft, hlens, targets,
                       cxe, emit, r0);
  }
  hipLaunchKernelGGL(ctc_fwd, dim3(B_), dim3(64), 0, stream, emit, hlens, targets, olens, ctco);
  hipLaunchKernelGGL(final_reduce, dim3(1), blk, 0, stream, cxe, ctco, out);
}

// Round 4
// 210.800 us; speedup vs baseline: 4.1301x; 1.2768x over previous
//
#include <hip/hip_runtime.h>
#include <math.h>

#define LOG2E 1.4426950408889634f
#define LN2 0.6931471805599453f

constexpr int B_ = 16;
constexpr int T_ = 512;
constexpr int E_ = 512;    // K of GEMM
constexpr int V_ = 5000;   // true N
constexpr int VP_ = 5120;  // padded N (multiple of 128)
constexpr int L_ = 64;
constexpr int S_ = 2 * L_ + 1;  // 129
constexpr int SP_ = 132;        // padded emit stride (16B-aligned rows)

typedef __attribute__((ext_vector_type(8))) short bf16x8;
typedef __attribute__((ext_vector_type(4))) float f32x4;

#define GLOAD_LDS16(g, l)                                                              \
  __builtin_amdgcn_global_load_lds((const __attribute__((address_space(1))) void*)(g), \
                                   (__attribute__((address_space(3))) void*)(l), 16, 0, 0)

__device__ __forceinline__ unsigned short f2bf(float x) {
  unsigned int u = __float_as_uint(x);
  unsigned int r = (u + 0x7fffu + ((u >> 16) & 1u)) >> 16;  // RNE
  return (unsigned short)r;
}
__device__ __forceinline__ float bf2f(unsigned int lo16) {
  return __uint_as_float(lo16 << 16);
}

__device__ __forceinline__ float hexp2(float x) { return __builtin_amdgcn_exp2f(x); }
__device__ __forceinline__ float hlog2(float x) { return __builtin_amdgcn_logf(x); }

// neighbor a1 from lane-1 via DPP: row_shr:1, boundary lanes patched by row_bcast15,
// lane 0 gets 0.0 (prob-domain zero).
__device__ __forceinline__ float dpp_shr1_zero(float v) {
  int s = __float_as_int(v);
  int bc = __builtin_amdgcn_update_dpp(0, s, 0x142, 0xF, 0xF, false);   // row_bcast15
  int r = __builtin_amdgcn_update_dpp(bc, s, 0x111, 0xF, 0xF, false);   // row_shr:1
  return __int_as_float(r);
}

template <int CTRL>
__device__ __forceinline__ float dpp_mv(float v) {
  int s = __float_as_int(v);
  return __int_as_float(__builtin_amdgcn_update_dpp(s, s, CTRL, 0xF, 0xF, false));
}

// ---------- block reduction helper (256 threads = 4 waves of 64) ----------
__device__ __forceinline__ float blockReduceF(float v, bool is_max, volatile float* red) {
  int tid = threadIdx.x, lane = tid & 63, wid = tid >> 6;
#pragma unroll
  for (int off = 32; off > 0; off >>= 1) {
    float o = __shfl_down(v, off, 64);
    v = is_max ? fmaxf(v, o) : (v + o);
  }
  __syncthreads();
  if (lane == 0) red[wid] = v;
  __syncthreads();
  float r = red[0];
#pragma unroll
  for (int w = 1; w < 4; ++w) r = is_max ? fmaxf(r, (float)red[w]) : (r + (float)red[w]);
  return r;
}

// ---------- conversion: hs_pad f32 -> bf16 ----------
__global__ __launch_bounds__(256) void convA(const float* __restrict__ X,
                                             unsigned short* __restrict__ Y, int n4) {
  int i = blockIdx.x * 256 + threadIdx.x;
  if (i >= n4) return;
  float4 v = ((const float4*)X)[i];
  ushort4 o;
  o.x = f2bf(v.x); o.y = f2bf(v.y); o.z = f2bf(v.z); o.w = f2bf(v.w);
  ((ushort4*)Y)[i] = o;
}

// ---------- conversion: W [512][5000] f32 -> W_T [5120][512] bf16 ----------
__global__ __launch_bounds__(256) void convW(const float* __restrict__ W,
                                             unsigned short* __restrict__ Wt) {
  __shared__ float tile[32][33];
  int n0 = blockIdx.x * 32, k0 = blockIdx.y * 32;
  int tid = threadIdx.x;
  int tx = tid & 31, ty = tid >> 5;
#pragma unroll
  for (int p = 0; p < 4; ++p) {
    int k = k0 + ty + p * 8, n = n0 + tx;
    tile[ty + p * 8][tx] = (n < V_) ? W[(size_t)k * V_ + n] : 0.0f;
  }
  __syncthreads();
#pragma unroll
  for (int p = 0; p < 4; ++p) {
    int n = n0 + ty + p * 8, k = k0 + tx;
    Wt[(size_t)n * E_ + k] = f2bf(tile[tx][ty + p * 8]);
  }
}

// ---------- Kernel A: bf16 MFMA GEMM, C output in bf16 ----------
__global__ __launch_bounds__(256) void gemm_mfma(const unsigned short* __restrict__ A,
                                                 const unsigned short* __restrict__ Wt,
                                                 const float* __restrict__ bias,
                                                 unsigned short* __restrict__ C) {
  __shared__ unsigned short As[128 * 32];
  __shared__ unsigned short Bs[128 * 32];
  int tid = threadIdx.x;
  int l = tid & 63, wid = tid >> 6;
  int lane15 = l & 15, lhalf = l >> 4;
  int wr = wid >> 1, wc = wid & 1;
  int bm = blockIdx.y * 128;
  int bn = blockIdx.x * 128;

  f32x4 acc[4][4] = {};

  int srow = l >> 2;
  int scol = (l & 3) * 8;
  for (int k0 = 0; k0 < E_; k0 += 32) {
#pragma unroll
    for (int i = 0; i < 2; ++i) {
      int rb = wid * 32 + i * 16;
      GLOAD_LDS16(A + (size_t)(bm + rb + srow) * E_ + k0 + scol, &As[rb * 32]);
      GLOAD_LDS16(Wt + (size_t)(bn + rb + srow) * E_ + k0 + scol, &Bs[rb * 32]);
    }
    __syncthreads();
    bf16x8 af[4], bf[4];
#pragma unroll
    for (int m = 0; m < 4; ++m)
      af[m] = *(const bf16x8*)&As[(wr * 64 + m * 16 + lane15) * 32 + lhalf * 8];
#pragma unroll
    for (int n = 0; n < 4; ++n)
      bf[n] = *(const bf16x8*)&Bs[(wc * 64 + n * 16 + lane15) * 32 + lhalf * 8];
#pragma unroll
    for (int m = 0; m < 4; ++m)
#pragma unroll
      for (int n = 0; n < 4; ++n)
        acc[m][n] = __builtin_amdgcn_mfma_f32_16x16x32_bf16(af[m], bf[n], acc[m][n], 0, 0, 0);
    __syncthreads();
  }

#pragma unroll
  for (int n = 0; n < 4; ++n) {
    int col = bn + wc * 64 + n * 16 + lane15;
    float bv = (col < V_) ? bias[col] : 0.0f;
#pragma unroll
    for (int m = 0; m < 4; ++m) {
      int row0 = bm + wr * 64 + m * 16 + lhalf * 4;
#pragma unroll
      for (int j = 0; j < 4; ++j) {
        C[(size_t)(row0 + j) * VP_ + col] = f2bf(acc[m][n][j] + bv);
      }
    }
  }
}

// ---------- Kernel B: per-row log-softmax + KD term + scaled CTC emissions ----------
__global__ __launch_bounds__(256) void row_fused(const unsigned short* __restrict__ Cc,
                                                 const float* __restrict__ soft,
                                                 const int* __restrict__ hlens,
                                                 const int* __restrict__ targets,
                                                 float* __restrict__ cxe,
                                                 float* __restrict__ emit, int r0) {
  int r = blockIdx.x;
  int row = r0 + r;
  int bidx = row >> 9;
  int t = row & (T_ - 1);
  const uint4* lrow = (const uint4*)(Cc + (size_t)r * VP_);
  const float4* srow = (const float4*)(soft + (size_t)row * V_);
  __shared__ __align__(16) float Ls[V_];
  __shared__ __align__(16) float Ss[V_];
  __shared__ float esh[S_ + 3];
  __shared__ float red[4];
  int tid = threadIdx.x;
  float maxl = -INFINITY, maxs = -INFINITY;
  for (int i = tid; i < V_ / 8; i += 256) {  // 625 groups of 8 bf16
    uint4 u = lrow[i];
    float f0 = bf2f(u.x & 0xffffu), f1 = bf2f(u.x >> 16);
    float f2 = bf2f(u.y & 0xffffu), f3 = bf2f(u.y >> 16);
    float f4 = bf2f(u.z & 0xffffu), f5 = bf2f(u.z >> 16);
    float f6 = bf2f(u.w & 0xffffu), f7 = bf2f(u.w >> 16);
    Ls[i * 8 + 0] = f0; Ls[i * 8 + 1] = f1; Ls[i * 8 + 2] = f2; Ls[i * 8 + 3] = f3;
    Ls[i * 8 + 4] = f4; Ls[i * 8 + 5] = f5; Ls[i * 8 + 6] = f6; Ls[i * 8 + 7] = f7;
    maxl = fmaxf(fmaxf(fmaxf(maxl, f0), fmaxf(f1, f2)),
                 fmaxf(fmaxf(f3, f4), fmaxf(fmaxf(f5, f6), f7)));
  }
  for (int i = tid; i < V_ / 4; i += 256) {
    float4 sv = srow[i];
    *(float4*)&Ss[i * 4] = sv;
    maxs = fmaxf(fmaxf(fmaxf(maxs, sv.x), fmaxf(sv.y, sv.z)), sv.w);
  }
  maxl = blockReduceF(maxl, true, red);
  maxs = blockReduceF(maxs, true, red);
  float suml = 0.f, sums = 0.f, dot = 0.f;
  for (int i = tid; i < V_; i += 256) {
    float l = Ls[i], s = Ss[i];
    suml += hexp2((l - maxl) * LOG2E);
    float e = hexp2((s - maxs) * LOG2E);
    sums += e;
    dot += e * l;
  }
  suml = blockReduceF(suml, false, red);
  sums = blockReduceF(sums, false, red);
  dot = blockReduceF(dot, false, red);
  float lse = maxl + hlog2(suml) * LN2;
  if (tid == 0) {
    cxe[row] = (t < hlens[bidx]) ? (lse - dot / sums) : 0.0f;
  }
  // scaled emissions: esh[s] = log2 p(ext_s); K = max_s; store 2^(esh-K) and K
  if (tid < S_) {
    int idx = (tid & 1) ? targets[bidx * L_ + (tid >> 1)] : 0;  // blank = 0
    esh[tid] = (Ls[idx] - lse) * LOG2E;
  }
  __syncthreads();
  if (tid < 64) {
    float m = fmaxf(esh[tid], esh[tid + 64]);
    if (tid == 0) m = fmaxf(m, esh[128]);
#pragma unroll
    for (int off = 32; off > 0; off >>= 1) m = fmaxf(m, __shfl_xor(m, off, 64));
    if (tid == 0) esh[S_ + 1] = m;
  }
  __syncthreads();
  float K = esh[S_ + 1];
  float* erow = emit + ((size_t)bidx * T_ + t) * SP_;
  if (tid < S_) erow[tid] = hexp2(esh[tid] - K);
  if (tid == 0) erow[130] = K;
}

// ---------- Kernel C: CTC forward, prob domain, DPP neighbor, renorm every 8 ----------
__device__ __forceinline__ void pstep(float& a0, float& a1, float& a2, float allowf,
                                      float e0, float e1, float e2) {
  float ua1 = dpp_shr1_zero(a1);
  float n0 = (a0 + ua1) * e0;
  float n1 = fmaf(ua1, allowf, a0 + a1) * e1;
  float n2 = (a2 + a1) * e2;
  a0 = n0; a1 = n1; a2 = n2;
}

__device__ __forceinline__ void renorm(float& a0, float& a1, float& a2, float& shift,
                                       int lane) {
  float m = fmaxf(a0, a1);
  m = (lane == 63) ? fmaxf(m, a2) : m;
  m = fmaxf(m, dpp_mv<0xB1>(m));    // quad xor1
  m = fmaxf(m, dpp_mv<0x4E>(m));    // quad xor2
  m = fmaxf(m, dpp_mv<0x124>(m));   // row_ror:4
  m = fmaxf(m, dpp_mv<0x128>(m));   // row_ror:8
  m = fmaxf(m, __shfl_xor(m, 16, 64));
  m = fmaxf(m, __shfl_xor(m, 32, 64));
  m = fmaxf(m, 1e-35f);
  float rs = __builtin_amdgcn_rcpf(m) * 281474976710656.0f;  // *2^48 headroom
  a0 *= rs; a1 *= rs; a2 *= rs;
  shift -= hlog2(rs);
}

__global__ __launch_bounds__(64) void ctc_fwd(const float* __restrict__ emit,
                                              const int* __restrict__ hlens,
                                              const int* __restrict__ targets,
                                              const int* __restrict__ olens,
                                              float* __restrict__ ctc_out) {
  int b = blockIdx.x;
  int l = threadIdx.x;  // 0..63
  const float* Eb = emit + (size_t)b * T_ * SP_;
  float allowf = 0.f;
  if (l >= 1) allowf = (targets[b * L_ + l] != targets[b * L_ + l - 1]) ? 1.0f : 0.0f;

  float a0, a1, a2, shift;
  {
    float2 e01 = *(const float2*)(Eb + 2 * l);
    float4 x = *(const float4*)(Eb + 128);
    a0 = (l == 0) ? e01.x : 0.0f;
    a1 = (l == 0) ? e01.y : 0.0f;
    a2 = 0.0f;
    shift = x.z;  // K_0
  }
  int ilen = hlens[b];

#define LDE(tt) (*(const float2*)(Eb + (size_t)(tt) * SP_ + 2 * l))
#define LDX(tt) (*(const float4*)(Eb + (size_t)(tt) * SP_ + 128))

  float2 c0 = LDE(1), c1 = LDE(2), c2 = LDE(3), c3 = LDE(4);
  float2 c4 = LDE(5), c5 = LDE(6), c6 = LDE(7), c7 = LDE(8);
  float4 x0 = LDX(1), x1 = LDX(2), x2 = LDX(3), x3 = LDX(4);
  float4 x4 = LDX(5), x5 = LDX(6), x6 = LDX(7), x7 = LDX(8);

  int t = 1;
  for (; t + 7 <= ilen - 1; t += 8) {
    float2 p0 = LDE(t + 8), p1 = LDE(t + 9), p2 = LDE(t + 10), p3 = LDE(t + 11);
    float2 p4 = LDE(t + 12), p5 = LDE(t + 13), p6 = LDE(t + 14), p7 = LDE(t + 15);
    float4 q0 = LDX(t + 8), q1 = LDX(t + 9), q2 = LDX(t + 10), q3 = LDX(t + 11);
    float4 q4 = LDX(t + 12), q5 = LDX(t + 13), q6 = LDX(t + 14), q7 = LDX(t + 15);
    pstep(a0, a1, a2, allowf, c0.x, c0.y, x0.x);
    pstep(a0, a1, a2, allowf, c1.x, c1.y, x1.x);
    pstep(a0, a1, a2, allowf, c2.x, c2.y, x2.x);
    pstep(a0, a1, a2, allowf, c3.x, c3.y, x3.x);
    pstep(a0, a1, a2, allowf, c4.x, c4.y, x4.x);
    pstep(a0, a1, a2, allowf, c5.x, c5.y, x5.x);
    pstep(a0, a1, a2, allowf, c6.x, c6.y, x6.x);
    pstep(a0, a1, a2, allowf, c7.x, c7.y, x7.x);
    shift += ((x0.z + x1.z) + (x2.z + x3.z)) + ((x4.z + x5.z) + (x6.z + x7.z));
    renorm(a0, a1, a2, shift, l);
    c0 = p0; c1 = p1; c2 = p2; c3 = p3; c4 = p4; c5 = p5; c6 = p6; c7 = p7;
    x0 = q0; x1 = q1; x2 = q2; x3 = q3; x4 = q4; x5 = q5; x6 = q6; x7 = q7;
  }
  // tail: <= 7 steps, data already in c0..c6/x0..x6
  int rem = ilen - t;  // steps remaining
  if (rem > 0) { pstep(a0, a1, a2, allowf, c0.x, c0.y, x0.x); shift += x0.z; }
  if (rem > 1) { pstep(a0, a1, a2, allowf, c1.x, c1.y, x1.x); shift += x1.z; }
  if (rem > 2) { pstep(a0, a1, a2, allowf, c2.x, c2.y, x2.x); shift += x2.z; }
  if (rem > 3) { pstep(a0, a1, a2, allowf, c3.x, c3.y, x3.x); shift += x3.z; }
  if (rem > 4) { pstep(a0, a1, a2, allowf, c4.x, c4.y, x4.x); shift += x4.z; }
  if (rem > 5) { pstep(a0, a1, a2, allowf, c5.x, c5.y, x5.x); shift += x5.z; }
  if (rem > 6) { pstep(a0, a1, a2, allowf, c6.x, c6.y, x6.x); shift += x6.z; }
#undef LDE
#undef LDX

  int end = 2 * olens[b];  // 64..128, even
  float aE = (end == 128) ? __shfl(a2, 63, 64) : __shfl(a0, end >> 1, 64);
  float aE1 = __shfl(a1, (end >> 1) - 1, 64);
  if (l == 0) {
    float p = aE + aE1;
    float ll = (hlog2(p) + shift) * LN2;
    float loss = -ll;
    if (!(loss <= 1e20f)) loss = 0.0f;  // zero_infinity (also catches inf/nan)
    ctc_out[b] = loss;
  }
}

// ---------- Kernel D: final combine ----------
__global__ __launch_bounds__(256) void final_reduce(const float* __restrict__ cxe,
                                                    const float* __restrict__ ctco,
                                                    float* __restrict__ out) {
  __shared__ float red[4];
  float s = 0.f;
  for (int i = threadIdx.x; i < B_ * T_; i += 256) s += cxe[i];
  s = blockReduceF(s, false, red);
  if (threadIdx.x == 0) {
    float c = 0.f;
    for (int b = 0; b < B_; ++b) c += ctco[b];
    out[0] = 0.5f * (s / (float)B_) + 0.5f * (c / (float)B_);
  }
}

extern "C" void kernel_launch(void* const* d_in, const int* in_sizes, int n_in,
                              void* d_out, int out_size, void* d_ws, size_t ws_size,
                              hipStream_t stream) {
  const float* hs = (const float*)d_in[0];
  const float* soft = (const float*)d_in[1];
  const float* W = (const float*)d_in[2];
  const float* bias = (const float*)d_in[3];
  const int* hlens = (const int*)d_in[4];
  const int* targets = (const int*)d_in[5];
  const int* olens = (const int*)d_in[6];
  float* out = (float*)d_out;

  // workspace layout (emit has +16 rows slack for prefetch overrun)
  size_t emit_n = (size_t)(B_ * T_ + 16) * SP_;
  float* emit = (float*)d_ws;
  float* cxe = emit + emit_n;
  float* ctco = cxe + (size_t)B_ * T_;
  unsigned short* Abf = (unsigned short*)(ctco + 16);
  unsigned short* Wt = Abf + (size_t)B_ * T_ * E_;
  unsigned short* logits = Wt + (size_t)VP_ * E_;  // bf16 chunk buffer
  size_t used = (size_t)((char*)logits - (char*)d_ws);
  size_t avail = (ws_size > used) ? (ws_size - used) : 0;
  int max_rows = (int)(avail / ((size_t)VP_ * sizeof(unsigned short)));
  int chunk = max_rows & ~127;
  int total = B_ * T_;
  if (chunk > total) chunk = total;
  if (chunk < 128) chunk = 128;

  dim3 blk(256);
  {
    int n4 = total * E_ / 4;
    hipLaunchKernelGGL(convA, dim3((n4 + 255) / 256), blk, 0, stream, hs, Abf, n4);
    hipLaunchKernelGGL(convW, dim3(VP_ / 32, E_ / 32), blk, 0, stream, W, Wt);
  }

  for (int r0 = 0; r0 < total; r0 += chunk) {
    int mc = total - r0;
    if (mc > chunk) mc = chunk;
    dim3 g1(VP_ / 128, mc / 128);
    hipLaunchKernelGGL(gemm_mfma, g1, blk, 0, stream, Abf + (size_t)r0 * E_, Wt, bias, logits);
    hipLaunchKernelGGL(row_fused, dim3(mc), blk, 0, stream, logits, soft, hlens, targets,
                       cxe, emit, r0);
  }
  hipLaunchKernelGGL(ctc_fwd, dim3(B_), dim3(64), 0, stream, emit, hlens, targets, olens, ctco);
  hipLaunchKernelGGL(final_reduce, dim3(1), blk, 0, stream, cxe, ctco, out);
}

// Round 5
// 178.459 us; speedup vs baseline: 4.8786x; 1.1812x over previous
//
#include <hip/hip_runtime.h>
#include <math.h>

#define LOG2E 1.4426950408889634f
#define LN2 0.6931471805599453f

constexpr int B_ = 16;
constexpr int T_ = 512;
constexpr int E_ = 512;    // K of GEMM
constexpr int V_ = 5000;   // true N
constexpr int VP_ = 5120;  // padded N (multiple of 128)
constexpr int L_ = 64;
constexpr int S_ = 2 * L_ + 1;  // 129
constexpr int SP_ = 132;        // padded emit stride (16B-aligned rows)

typedef __attribute__((ext_vector_type(8))) short bf16x8;
typedef __attribute__((ext_vector_type(4))) float f32x4;

#define GLOAD_LDS16(g, l)                                                              \
  __builtin_amdgcn_global_load_lds((const __attribute__((address_space(1))) void*)(g), \
                                   (__attribute__((address_space(3))) void*)(l), 16, 0, 0)

__device__ __forceinline__ unsigned short f2bf(float x) {
  unsigned int u = __float_as_uint(x);
  unsigned int r = (u + 0x7fffu + ((u >> 16) & 1u)) >> 16;  // RNE
  return (unsigned short)r;
}
__device__ __forceinline__ float bf2f(unsigned int lo16) {
  return __uint_as_float(lo16 << 16);
}

__device__ __forceinline__ float hexp2(float x) { return __builtin_amdgcn_exp2f(x); }
__device__ __forceinline__ float hlog2(float x) { return __builtin_amdgcn_logf(x); }

// neighbor a1 from lane-1 via DPP: row_shr:1 with row_bcast15 patch; lane0 -> 0
__device__ __forceinline__ float dpp_shr1_zero(float v) {
  int s = __float_as_int(v);
  int bc = __builtin_amdgcn_update_dpp(0, s, 0x142, 0xF, 0xF, false);   // row_bcast15
  int r = __builtin_amdgcn_update_dpp(bc, s, 0x111, 0xF, 0xF, false);   // row_shr:1
  return __int_as_float(r);
}

template <int CTRL>
__device__ __forceinline__ float dpp_mv(float v) {
  int s = __float_as_int(v);
  return __int_as_float(__builtin_amdgcn_update_dpp(s, s, CTRL, 0xF, 0xF, false));
}

// ---------- block reduction helper (256 threads = 4 waves of 64) ----------
__device__ __forceinline__ float blockReduceF(float v, bool is_max, volatile float* red) {
  int tid = threadIdx.x, lane = tid & 63, wid = tid >> 6;
#pragma unroll
  for (int off = 32; off > 0; off >>= 1) {
    float o = __shfl_down(v, off, 64);
    v = is_max ? fmaxf(v, o) : (v + o);
  }
  __syncthreads();
  if (lane == 0) red[wid] = v;
  __syncthreads();
  float r = red[0];
#pragma unroll
  for (int w = 1; w < 4; ++w) r = is_max ? fmaxf(r, (float)red[w]) : (r + (float)red[w]);
  return r;
}

// ---------- conversion: hs_pad f32 -> bf16 ----------
__global__ __launch_bounds__(256) void convA(const float* __restrict__ X,
                                             unsigned short* __restrict__ Y, int n4) {
  int i = blockIdx.x * 256 + threadIdx.x;
  if (i >= n4) return;
  float4 v = ((const float4*)X)[i];
  ushort4 o;
  o.x = f2bf(v.x); o.y = f2bf(v.y); o.z = f2bf(v.z); o.w = f2bf(v.w);
  ((ushort4*)Y)[i] = o;
}

// ---------- conversion: W [512][5000] f32 -> W_T [5120][512] bf16 ----------
__global__ __launch_bounds__(256) void convW(const float* __restrict__ W,
                                             unsigned short* __restrict__ Wt) {
  __shared__ float tile[32][33];
  int n0 = blockIdx.x * 32, k0 = blockIdx.y * 32;
  int tid = threadIdx.x;
  int tx = tid & 31, ty = tid >> 5;
#pragma unroll
  for (int p = 0; p < 4; ++p) {
    int k = k0 + ty + p * 8, n = n0 + tx;
    tile[ty + p * 8][tx] = (n < V_) ? W[(size_t)k * V_ + n] : 0.0f;
  }
  __syncthreads();
#pragma unroll
  for (int p = 0; p < 4; ++p) {
    int n = n0 + ty + p * 8, k = k0 + tx;
    Wt[(size_t)n * E_ + k] = f2bf(tile[tx][ty + p * 8]);
  }
}

// ---------- Kernel A: bf16 MFMA GEMM, C output in bf16 ----------
__global__ __launch_bounds__(256) void gemm_mfma(const unsigned short* __restrict__ A,
                                                 const unsigned short* __restrict__ Wt,
                                                 const float* __restrict__ bias,
                                                 unsigned short* __restrict__ C) {
  __shared__ unsigned short As[128 * 32];
  __shared__ unsigned short Bs[128 * 32];
  int tid = threadIdx.x;
  int l = tid & 63, wid = tid >> 6;
  int lane15 = l & 15, lhalf = l >> 4;
  int wr = wid >> 1, wc = wid & 1;
  int bm = blockIdx.y * 128;
  int bn = blockIdx.x * 128;

  f32x4 acc[4][4] = {};

  int srow = l >> 2;
  int scol = (l & 3) * 8;
  for (int k0 = 0; k0 < E_; k0 += 32) {
#pragma unroll
    for (int i = 0; i < 2; ++i) {
      int rb = wid * 32 + i * 16;
      GLOAD_LDS16(A + (size_t)(bm + rb + srow) * E_ + k0 + scol, &As[rb * 32]);
      GLOAD_LDS16(Wt + (size_t)(bn + rb + srow) * E_ + k0 + scol, &Bs[rb * 32]);
    }
    __syncthreads();
    bf16x8 af[4], bf[4];
#pragma unroll
    for (int m = 0; m < 4; ++m)
      af[m] = *(const bf16x8*)&As[(wr * 64 + m * 16 + lane15) * 32 + lhalf * 8];
#pragma unroll
    for (int n = 0; n < 4; ++n)
      bf[n] = *(const bf16x8*)&Bs[(wc * 64 + n * 16 + lane15) * 32 + lhalf * 8];
#pragma unroll
    for (int m = 0; m < 4; ++m)
#pragma unroll
      for (int n = 0; n < 4; ++n)
        acc[m][n] = __builtin_amdgcn_mfma_f32_16x16x32_bf16(af[m], bf[n], acc[m][n], 0, 0, 0);
    __syncthreads();
  }

#pragma unroll
  for (int n = 0; n < 4; ++n) {
    int col = bn + wc * 64 + n * 16 + lane15;
    float bv = (col < V_) ? bias[col] : 0.0f;
#pragma unroll
    for (int m = 0; m < 4; ++m) {
      int row0 = bm + wr * 64 + m * 16 + lhalf * 4;
#pragma unroll
      for (int j = 0; j < 4; ++j) {
        C[(size_t)(row0 + j) * VP_ + col] = f2bf(acc[m][n][j] + bv);
      }
    }
  }
}

// ---------- Kernel B: per-row stats fully in registers (no big LDS) ----------
// Each thread owns 3 slots of 8 consecutive vocab entries (625 uint4 groups total).
__global__ __launch_bounds__(256) void row_fused(const unsigned short* __restrict__ Cc,
                                                 const float* __restrict__ soft,
                                                 const int* __restrict__ hlens,
                                                 const int* __restrict__ targets,
                                                 float* __restrict__ cxe,
                                                 float* __restrict__ emit, int r0) {
  int r = blockIdx.x;
  int row = r0 + r;
  int bidx = row >> 9;
  int t = row & (T_ - 1);
  const unsigned short* crow = Cc + (size_t)r * VP_;
  const uint4* lrow = (const uint4*)crow;
  const float4* srow = (const float4*)(soft + (size_t)row * V_);
  __shared__ float red[4];
  int tid = threadIdx.x;

  uint4 lu[3];
  float4 sv[3][2];
  bool valid[3];
#pragma unroll
  for (int k = 0; k < 3; ++k) {
    int slot = tid + k * 256;
    valid[k] = (slot < V_ / 8);  // 625
    if (valid[k]) {
      lu[k] = lrow[slot];
      sv[k][0] = srow[slot * 2];
      sv[k][1] = srow[slot * 2 + 1];
    }
  }

  // pass 1: maxima from registers
  float maxl = -INFINITY, maxs = -INFINITY;
#pragma unroll
  for (int k = 0; k < 3; ++k) {
    if (valid[k]) {
      unsigned int w0 = lu[k].x, w1 = lu[k].y, w2 = lu[k].z, w3 = lu[k].w;
      maxl = fmaxf(maxl, fmaxf(fmaxf(bf2f(w0 & 0xffffu), bf2f(w0 >> 16)),
                               fmaxf(bf2f(w1 & 0xffffu), bf2f(w1 >> 16))));
      maxl = fmaxf(maxl, fmaxf(fmaxf(bf2f(w2 & 0xffffu), bf2f(w2 >> 16)),
                               fmaxf(bf2f(w3 & 0xffffu), bf2f(w3 >> 16))));
      float4 a = sv[k][0], b = sv[k][1];
      maxs = fmaxf(maxs, fmaxf(fmaxf(a.x, a.y), fmaxf(a.z, a.w)));
      maxs = fmaxf(maxs, fmaxf(fmaxf(b.x, b.y), fmaxf(b.z, b.w)));
    }
  }
  maxl = blockReduceF(maxl, true, red);
  maxs = blockReduceF(maxs, true, red);

  // pass 2: sums from registers
  float suml = 0.f, sums = 0.f, dot = 0.f;
#pragma unroll
  for (int k = 0; k < 3; ++k) {
    if (valid[k]) {
      float lv[8], ss[8];
      unsigned int w0 = lu[k].x, w1 = lu[k].y, w2 = lu[k].z, w3 = lu[k].w;
      lv[0] = bf2f(w0 & 0xffffu); lv[1] = bf2f(w0 >> 16);
      lv[2] = bf2f(w1 & 0xffffu); lv[3] = bf2f(w1 >> 16);
      lv[4] = bf2f(w2 & 0xffffu); lv[5] = bf2f(w2 >> 16);
      lv[6] = bf2f(w3 & 0xffffu); lv[7] = bf2f(w3 >> 16);
      float4 a = sv[k][0], b = sv[k][1];
      ss[0] = a.x; ss[1] = a.y; ss[2] = a.z; ss[3] = a.w;
      ss[4] = b.x; ss[5] = b.y; ss[6] = b.z; ss[7] = b.w;
#pragma unroll
      for (int j = 0; j < 8; ++j) {
        suml += hexp2((lv[j] - maxl) * LOG2E);
        float e = hexp2((ss[j] - maxs) * LOG2E);
        sums += e;
        dot = fmaf(e, lv[j], dot);
      }
    }
  }
  suml = blockReduceF(suml, false, red);
  sums = blockReduceF(sums, false, red);
  dot = blockReduceF(dot, false, red);

  float lse = maxl + hlog2(suml) * LN2;
  if (tid == 0) {
    cxe[row] = (t < hlens[bidx]) ? (lse - dot / sums) : 0.0f;
  }

  // wave 0: emission gather (129 label logits) + wave max + scaled store
  if (tid < 64) {
    int i0 = tid, i1 = tid + 64;
    int idx0 = (i0 & 1) ? targets[bidx * L_ + (i0 >> 1)] : 0;
    int idx1 = (i1 & 1) ? targets[bidx * L_ + (i1 >> 1)] : 0;
    float e0 = (bf2f(crow[idx0]) - lse) * LOG2E;
    float e1 = (bf2f(crow[idx1]) - lse) * LOG2E;
    float e2 = 0.f;
    if (tid == 0) e2 = (bf2f(crow[0]) - lse) * LOG2E;  // s=128 blank
    float m = fmaxf(e0, e1);
    if (tid == 0) m = fmaxf(m, e2);
#pragma unroll
    for (int off = 32; off > 0; off >>= 1) m = fmaxf(m, __shfl_xor(m, off, 64));
    float* erow = emit + ((size_t)bidx * T_ + t) * SP_;
    erow[i0] = hexp2(e0 - m);
    erow[i1] = hexp2(e1 - m);
    if (tid == 0) {
      erow[128] = hexp2(e2 - m);
      erow[130] = m;  // K_t
    }
  }
}

// ---------- Kernel C: CTC forward, prob domain, DPP neighbor, renorm every 8 ----------
__device__ __forceinline__ void pstep(float& a0, float& a1, float& a2, float allowf,
                                      float e0, float e1, float e2) {
  float ua1 = dpp_shr1_zero(a1);
  float n0 = (a0 + ua1) * e0;
  float n1 = fmaf(ua1, allowf, a0 + a1) * e1;
  float n2 = (a2 + a1) * e2;
  a0 = n0; a1 = n1; a2 = n2;
}

__device__ __forceinline__ void renorm(float& a0, float& a1, float& a2, float& shift,
                                       int lane) {
  float m = fmaxf(a0, a1);
  m = (lane == 63) ? fmaxf(m, a2) : m;
  m = fmaxf(m, dpp_mv<0xB1>(m));    // quad xor1
  m = fmaxf(m, dpp_mv<0x4E>(m));    // quad xor2
  m = fmaxf(m, dpp_mv<0x124>(m));   // row_ror:4
  m = fmaxf(m, dpp_mv<0x128>(m));   // row_ror:8
  m = fmaxf(m, __shfl_xor(m, 16, 64));
  m = fmaxf(m, __shfl_xor(m, 32, 64));
  m = fmaxf(m, 1e-35f);
  float rs = __builtin_amdgcn_rcpf(m) * 281474976710656.0f;  // *2^48 headroom
  a0 *= rs; a1 *= rs; a2 *= rs;
  shift -= hlog2(rs);
}

__global__ __launch_bounds__(64) void ctc_fwd(const float* __restrict__ emit,
                                              const int* __restrict__ hlens,
                                              const int* __restrict__ targets,
                                              const int* __restrict__ olens,
                                              float* __restrict__ ctc_out) {
  int b = blockIdx.x;
  int l = threadIdx.x;  // 0..63
  const float* Eb = emit + (size_t)b * T_ * SP_;
  float allowf = 0.f;
  if (l >= 1) allowf = (targets[b * L_ + l] != targets[b * L_ + l - 1]) ? 1.0f : 0.0f;

  float a0, a1, a2, shift;
  {
    float2 e01 = *(const float2*)(Eb + 2 * l);
    float4 x = *(const float4*)(Eb + 128);
    a0 = (l == 0) ? e01.x : 0.0f;
    a1 = (l == 0) ? e01.y : 0.0f;
    a2 = 0.0f;
    shift = x.z;  // K_0
  }
  int ilen = hlens[b];

#define LDE(tt) (*(const float2*)(Eb + (size_t)(tt) * SP_ + 2 * l))
#define LDX(tt) (*(const float4*)(Eb + (size_t)(tt) * SP_ + 128))

  float2 c0 = LDE(1), c1 = LDE(2), c2 = LDE(3), c3 = LDE(4);
  float2 c4 = LDE(5), c5 = LDE(6), c6 = LDE(7), c7 = LDE(8);
  float4 x0 = LDX(1), x1 = LDX(2), x2 = LDX(3), x3 = LDX(4);
  float4 x4 = LDX(5), x5 = LDX(6), x6 = LDX(7), x7 = LDX(8);

  int t = 1;
  for (; t + 7 <= ilen - 1; t += 8) {
    float2 p0 = LDE(t + 8), p1 = LDE(t + 9), p2 = LDE(t + 10), p3 = LDE(t + 11);
    float2 p4 = LDE(t + 12), p5 = LDE(t + 13), p6 = LDE(t + 14), p7 = LDE(t + 15);
    float4 q0 = LDX(t + 8), q1 = LDX(t + 9), q2 = LDX(t + 10), q3 = LDX(t + 11);
    float4 q4 = LDX(t + 12), q5 = LDX(t + 13), q6 = LDX(t + 14), q7 = LDX(t + 15);
    pstep(a0, a1, a2, allowf, c0.x, c0.y, x0.x);
    pstep(a0, a1, a2, allowf, c1.x, c1.y, x1.x);
    pstep(a0, a1, a2, allowf, c2.x, c2.y, x2.x);
    pstep(a0, a1, a2, allowf, c3.x, c3.y, x3.x);
    pstep(a0, a1, a2, allowf, c4.x, c4.y, x4.x);
    pstep(a0, a1, a2, allowf, c5.x, c5.y, x5.x);
    pstep(a0, a1, a2, allowf, c6.x, c6.y, x6.x);
    pstep(a0, a1, a2, allowf, c7.x, c7.y, x7.x);
    shift += ((x0.z + x1.z) + (x2.z + x3.z)) + ((x4.z + x5.z) + (x6.z + x7.z));
    renorm(a0, a1, a2, shift, l);
    c0 = p0; c1 = p1; c2 = p2; c3 = p3; c4 = p4; c5 = p5; c6 = p6; c7 = p7;
    x0 = q0; x1 = q1; x2 = q2; x3 = q3; x4 = q4; x5 = q5; x6 = q6; x7 = q7;
  }
  int rem = ilen - t;
  if (rem > 0) { pstep(a0, a1, a2, allowf, c0.x, c0.y, x0.x); shift += x0.z; }
  if (rem > 1) { pstep(a0, a1, a2, allowf, c1.x, c1.y, x1.x); shift += x1.z; }
  if (rem > 2) { pstep(a0, a1, a2, allowf, c2.x, c2.y, x2.x); shift += x2.z; }
  if (rem > 3) { pstep(a0, a1, a2, allowf, c3.x, c3.y, x3.x); shift += x3.z; }
  if (rem > 4) { pstep(a0, a1, a2, allowf, c4.x, c4.y, x4.x); shift += x4.z; }
  if (rem > 5) { pstep(a0, a1, a2, allowf, c5.x, c5.y, x5.x); shift += x5.z; }
  if (rem > 6) { pstep(a0, a1, a2, allowf, c6.x, c6.y, x6.x); shift += x6.z; }
#undef LDE
#undef LDX

  int end = 2 * olens[b];  // 64..128, even
  float aE = (end == 128) ? __shfl(a2, 63, 64) : __shfl(a0, end >> 1, 64);
  float aE1 = __shfl(a1, (end >> 1) - 1, 64);
  if (l == 0) {
    float p = aE + aE1;
    float ll = (hlog2(p) + shift) * LN2;
    float loss = -ll;
    if (!(loss <= 1e20f)) loss = 0.0f;  // zero_infinity (catches inf/nan too)
    ctc_out[b] = loss;
  }
}

// ---------- Kernel D: final combine ----------
__global__ __launch_bounds__(256) void final_reduce(const float* __restrict__ cxe,
                                                    const float* __restrict__ ctco,
                                                    float* __restrict__ out) {
  __shared__ float red[4];
  float s = 0.f;
  for (int i = threadIdx.x; i < B_ * T_; i += 256) s += cxe[i];
  s = blockReduceF(s, false, red);
  if (threadIdx.x == 0) {
    float c = 0.f;
    for (int b = 0; b < B_; ++b) c += ctco[b];
    out[0] = 0.5f * (s / (float)B_) + 0.5f * (c / (float)B_);
  }
}

extern "C" void kernel_launch(void* const* d_in, const int* in_sizes, int n_in,
                              void* d_out, int out_size, void* d_ws, size_t ws_size,
                              hipStream_t stream) {
  const float* hs = (const float*)d_in[0];
  const float* soft = (const float*)d_in[1];
  const float* W = (const float*)d_in[2];
  const float* bias = (const float*)d_in[3];
  const int* hlens = (const int*)d_in[4];
  const int* targets = (const int*)d_in[5];
  const int* olens = (const int*)d_in[6];
  float* out = (float*)d_out;

  size_t emit_n = (size_t)(B_ * T_ + 16) * SP_;
  float* emit = (float*)d_ws;
  float* cxe = emit + emit_n;
  float* ctco = cxe + (size_t)B_ * T_;
  unsigned short* Abf = (unsigned short*)(ctco + 16);
  unsigned short* Wt = Abf + (size_t)B_ * T_ * E_;
  unsigned short* logits = Wt + (size_t)VP_ * E_;  // bf16 chunk buffer
  size_t used = (size_t)((char*)logits - (char*)d_ws);
  size_t avail = (ws_size > used) ? (ws_size - used) : 0;
  int max_rows = (int)(avail / ((size_t)VP_ * sizeof(unsigned short)));
  int chunk = max_rows & ~127;
  int total = B_ * T_;
  if (chunk > total) chunk = total;
  if (chunk < 128) chunk = 128;

  dim3 blk(256);
  {
    int n4 = total * E_ / 4;
    hipLaunchKernelGGL(convA, dim3((n4 + 255) / 256), blk, 0, stream, hs, Abf, n4);
    hipLaunchKernelGGL(convW, dim3(VP_ / 32, E_ / 32), blk, 0, stream, W, Wt);
  }

  for (int r0 = 0; r0 < total; r0 += chunk) {
    int mc = total - r0;
    if (mc > chunk) mc = chunk;
    dim3 g1(VP_ / 128, mc / 128);
    hipLaunchKernelGGL(gemm_mfma, g1, blk, 0, stream, Abf + (size_t)r0 * E_, Wt, bias, logits);
    hipLaunchKernelGGL(row_fused, dim3(mc), blk, 0, stream, logits, soft, hlens, targets,
                       cxe, emit, r0);
  }
  hipLaunchKernelGGL(ctc_fwd, dim3(B_), dim3(64), 0, stream, emit, hlens, targets, olens, ctco);
  hipLaunchKernelGGL(final_reduce, dim3(1), blk, 0, stream, cxe, ctco, out);
}